// Round 4
// baseline (1213.467 us; speedup 1.0000x reference)
//
#include <hip/hip_runtime.h>

// RNN B=256 T=2048 I=64 H=256 — one workgroup per sample, MFMA matvec recurrence.
// Serial-latency-bound: MfmaUtil 23% / VALUBusy 15% -> ~700cy/step of pure
// latency (ds_read, MFMA chain tail, barrier). Lever = TLP:
//   R2: 1 wave/SIMD = 1195us; R1: 2 waves/SIMD = 982us.
// R4: 4 waves/SIMD (16 waves, 1024 thr, wave owns 16 rows):
//  - per-wave step: 8 ds_read_b128 + 8 MFMA into 4 independent accs (chain
//    depth 2, was 4) + cheap extraction (no mt select) + 1 write.
//  - per-SIMD MFMA issue unchanged (4x8 = 2x16); fragment VGPRs halve.
//  - setprio DROPPED (R3: lockstep-symmetric waves -> pure overhead, -23us).
//  - kept: prefetch issued after mini-GEMM barrier (first vmcnt(0) drain is a
//    full step later), rcp-based tanh, per-block xp mini-GEMM, x2 step unroll.

static constexpr int nB = 256;
static constexpr int nT = 2048;
static constexpr int nI = 64;
static constexpr int nH = 256;
static constexpr int XBLK = 32;      // timesteps of x staged/projected per block
static constexpr int XSTR = 72;      // padded halfword stride of an xbuf row
static constexpr int THREADS = 1024; // 16 waves; wave w owns rows [16w,16w+16)

typedef _Float16 f16x8 __attribute__((ext_vector_type(8)));
typedef _Float16 f16x2 __attribute__((ext_vector_type(2)));
typedef float f32x4 __attribute__((ext_vector_type(4)));

__device__ __forceinline__ float fast_tanh(float x) {
  float a = fabsf(x);
  float e = __expf(-2.0f * a);           // in (0,1], never overflows
  float r = (1.0f - e) * __builtin_amdgcn_rcpf(1.0f + e);
  return copysignf(r, x);
}

__global__ __launch_bounds__(THREADS, 1)
void rnn_mfma(const float* __restrict__ x, const int* __restrict__ lengths,
              const float* __restrict__ Wih, const float* __restrict__ Whh,
              const float* __restrict__ bih, const float* __restrict__ bhh,
              const float* __restrict__ Wfc, const float* __restrict__ bfc,
              float* __restrict__ out)
{
  __shared__ __align__(16) _Float16 hbuf[2][nH];            // 1 KB
  __shared__ __align__(16) _Float16 xbuf[2][XBLK * XSTR];   // 9 KB
  __shared__ float xp[nH][XBLK + 1];                        // 33.8 KB
  __shared__ float red[THREADS / 64];

  const int b   = blockIdx.x;
  const int tid = threadIdx.x;
  const int w   = tid >> 6;       // wave 0..15
  const int l   = tid & 63;
  const int q   = l >> 4;         // quad 0..3
  const int n   = l & 15;         // MFMA column lane
  const int len = lengths[b];     // in [1, nT]
  const float* xb = x + (size_t)b * nT * nI;

  // ---- preamble: pack this wave's 16 W rows into A-fragments (f16)
  // A layout (16x16x32): lane holds A[m = lane&15][k = 8*(lane>>4) + j], j=0..7
  f16x8 Ah[8];   // W_hh row 16w+n, k = 32kt+8q+j
  f16x8 Ax[2];   // W_ih (I=64 -> 2 k-tiles), used only in the xp mini-GEMM
  {
    const int row = 16 * w + n;
#pragma unroll
    for (int kt = 0; kt < 8; ++kt) {
      const float* src = Whh + row * nH + 32 * kt + 8 * q;
      f16x8 a;
#pragma unroll
      for (int j = 0; j < 8; ++j) a[j] = (_Float16)src[j];
      Ah[kt] = a;
    }
#pragma unroll
    for (int kt = 0; kt < 2; ++kt) {
      const float* src = Wih + row * nI + 32 * kt + 8 * q;
      f16x8 a;
#pragma unroll
      for (int j = 0; j < 8; ++j) a[j] = (_Float16)src[j];
      Ax[kt] = a;
    }
  }
  // bias in C layout: reg r <-> row 16w + 4q + r (folded into xp)
  f32x4 biasC;
#pragma unroll
  for (int r = 0; r < 4; ++r) {
    const int r0 = 16 * w + 4 * q + r;
    biasC[r] = bih[r0] + bhh[r0];
  }
  // lanes n<4 each finish exactly one output row; others hold replicas
  const int reg_sel = n & 3;
  const int row_own = 16 * w + 4 * q + reg_sel;

  // x staging: 1024 thr x float2 = 2048 floats = one 32-step block
  const int offA = tid * 2;
  const int dstA = (offA >> 6) * XSTR + (offA & 63);

  // ---- h0 = 0; stage x block 0
  if (tid < nH) hbuf[0][tid] = (_Float16)0.f;
  {
    float2 v = *(const float2*)(xb + offA);
    f16x2 pv = { (_Float16)v.x, (_Float16)v.y };
    *(f16x2*)(xbuf[0] + dstA) = pv;
  }
  __syncthreads();

  int t = 0;
  for (int blk = 0; t < len; ++blk) {
    // ---- xp mini-GEMM: xp[row][s] = bias + W_ih . x_{blk*32+s}; timesteps
    // are the MFMA columns (ct=0 -> s=n, ct=1 -> s=16+n).
    {
      const _Float16* xB = xbuf[blk & 1];
      f32x4 g0 = biasC, g1 = biasC;
#pragma unroll
      for (int kt = 0; kt < 2; ++kt) {
        f16x8 B0 = *(const f16x8*)(xB + n * XSTR + 32 * kt + 8 * q);         // ct=0
        f16x8 B1 = *(const f16x8*)(xB + (16 + n) * XSTR + 32 * kt + 8 * q);  // ct=1
        g0 = __builtin_amdgcn_mfma_f32_16x16x32_f16(Ax[kt], B0, g0, 0, 0, 0);
        g1 = __builtin_amdgcn_mfma_f32_16x16x32_f16(Ax[kt], B1, g1, 0, 0, 0);
      }
#pragma unroll
      for (int r = 0; r < 4; ++r) {
        const int r0 = 16 * w + 4 * q + r;
        xp[r0][n]      = g0[r];
        xp[r0][16 + n] = g1[r];
      }
    }
    __syncthreads();

    // next-block x prefetch AFTER the barrier: first vmcnt(0) drain (step 0's
    // barrier) is a full step after issue -> HBM latency hidden.
    float2 pre;
    const bool havepre = ((blk + 1) * XBLK < len);
    if (havepre)
      pre = *(const float2*)(xb + (size_t)(blk + 1) * XBLK * nI + offA);

    const int nsteps = min(XBLK, len - blk * XBLK);

    auto step = [&](int s, const _Float16* hsrc, _Float16* hdst) {
      float xpv = xp[row_own][s];   // 16 rows/wave, 4-way replicated: conflict-free
      f32x4 z = {0.f, 0.f, 0.f, 0.f};
      f32x4 pa = z, pb = z, pc = z, pd = z;   // 4 partials: chain depth 2
      f16x8 B0 = *(const f16x8*)(hsrc + 8 * q);
      f16x8 B1 = *(const f16x8*)(hsrc + 8 * q + 32);
      f16x8 B2 = *(const f16x8*)(hsrc + 8 * q + 64);
      f16x8 B3 = *(const f16x8*)(hsrc + 8 * q + 96);
      f16x8 B4 = *(const f16x8*)(hsrc + 8 * q + 128);
      f16x8 B5 = *(const f16x8*)(hsrc + 8 * q + 160);
      f16x8 B6 = *(const f16x8*)(hsrc + 8 * q + 192);
      f16x8 B7 = *(const f16x8*)(hsrc + 8 * q + 224);
      pa = __builtin_amdgcn_mfma_f32_16x16x32_f16(Ah[0], B0, pa, 0, 0, 0);
      pb = __builtin_amdgcn_mfma_f32_16x16x32_f16(Ah[1], B1, pb, 0, 0, 0);
      pc = __builtin_amdgcn_mfma_f32_16x16x32_f16(Ah[2], B2, pc, 0, 0, 0);
      pd = __builtin_amdgcn_mfma_f32_16x16x32_f16(Ah[3], B3, pd, 0, 0, 0);
      pa = __builtin_amdgcn_mfma_f32_16x16x32_f16(Ah[4], B4, pa, 0, 0, 0);
      pb = __builtin_amdgcn_mfma_f32_16x16x32_f16(Ah[5], B5, pb, 0, 0, 0);
      pc = __builtin_amdgcn_mfma_f32_16x16x32_f16(Ah[6], B6, pc, 0, 0, 0);
      pd = __builtin_amdgcn_mfma_f32_16x16x32_f16(Ah[7], B7, pd, 0, 0, 0);
      f32x4 c = (pa + pb) + (pc + pd);
      float lo = (reg_sel & 1) ? c[1] : c[0];
      float hi = (reg_sel & 1) ? c[3] : c[2];
      float v  = ((reg_sel & 2) ? hi : lo) + xpv;
      float hn = fast_tanh(v);

      // fold next-x writeback in before this block's final barrier
      if (s == nsteps - 1 && havepre) {
        f16x2 pv = { (_Float16)pre.x, (_Float16)pre.y };
        *(f16x2*)(xbuf[(blk + 1) & 1] + dstA) = pv;
      }
      if (n < 4) hdst[row_own] = (_Float16)hn;
      __syncthreads();
    };

    // t parity == s parity (blk*XBLK even): unroll x2 with static buffers
    int s = 0;
    for (; s + 2 <= nsteps; s += 2) {
      step(s,     hbuf[0], hbuf[1]);
      step(s + 1, hbuf[1], hbuf[0]);
    }
    if (s < nsteps) step(s, hbuf[0], hbuf[1]);
    t += nsteps;
  }

  // ---- epilogue: out[b] = h_final . W_fc + b_fc
  float v = 0.f;
  if (tid < nH) v = (float)hbuf[len & 1][tid] * Wfc[tid];
#pragma unroll
  for (int off = 32; off; off >>= 1) v += __shfl_down(v, off);
  if (l == 0) red[w] = v;
  __syncthreads();
  if (tid == 0) {
    float acc = bfc[0];
#pragma unroll
    for (int i = 0; i < THREADS / 64; ++i) acc += red[i];
    out[b] = acc;
  }
}

extern "C" void kernel_launch(void* const* d_in, const int* in_sizes, int n_in,
                              void* d_out, int out_size, void* d_ws, size_t ws_size,
                              hipStream_t stream) {
  const float* x   = (const float*)d_in[0];
  const int* lens  = (const int*)d_in[1];
  const float* Wih = (const float*)d_in[2];
  const float* Whh = (const float*)d_in[3];
  const float* bih = (const float*)d_in[4];
  const float* bhh = (const float*)d_in[5];
  const float* Wfc = (const float*)d_in[6];
  const float* bfc = (const float*)d_in[7];
  float* out = (float*)d_out;

  rnn_mfma<<<nB, THREADS, 0, stream>>>(x, lens, Wih, Whh, bih, bhh, Wfc, bfc, out);
}